// Round 11
// baseline (390.659 us; speedup 1.0000x reference)
//
#include <hip/hip_runtime.h>
#include <hip/hip_bf16.h>

#define TT 512
#define BB 4096

typedef __attribute__((ext_vector_type(4))) float f32x4;
typedef __attribute__((ext_vector_type(8))) _Float16 f16x8;
typedef __attribute__((ext_vector_type(2))) unsigned int uint2v;
typedef __attribute__((ext_vector_type(4))) unsigned int uint4v;

__device__ __forceinline__ f32x4 MFMA16(f16x8 a, f16x8 b, f32x4 c) {
    return __builtin_amdgcn_mfma_f32_16x16x32_f16(a, b, c, 0, 0, 0);
}
__device__ __forceinline__ float fast_rcp(float x) { return __builtin_amdgcn_rcpf(x); }
__device__ __forceinline__ unsigned int pk2(float a, float b) {
    return __builtin_bit_cast(unsigned int, __builtin_amdgcn_cvt_pkrtz(a, b));
}

// Gate scaling folded into weights/biases (validated R9/R10):
//   r,z rows × -log2e -> gate = rcp(1+exp2(acc)); n rows × -2log2e -> tanh via exp2.
#define KS1 (-1.44269504088896340736f)
#define KS2 (-2.88539008177792681472f)

// Layer-pipelined GRU, TWO pipelines PER WAVE (chain interleaving in-stream):
//   waves 0..2 = layers (wave L does t=4(s-L)..+3 for BOTH pipes at superstep s),
//   wave 3 = projection+stores for both pipes (lag 3).
// Block = 256 thr = 4 waves, 32 batch cols (2 x 16-col pipelines); grid = 128.
// K=32 packing per pipe (R10, validated): k=8g+j; j<4 -> input dims 4g+j,
// j>=4 -> own-h dims. B = {upstream handoff (lane-aligned), own hC via cvt_pkrtz}.
// Weights are SHARED between the two pipes (same layer) — only state doubles.
__global__ __launch_bounds__(256, 1)
void gru_fk2_kernel(const float* __restrict__ x, const float* __restrict__ h0,
                    const float* __restrict__ W_emb, const float* __restrict__ b_emb,
                    const float* __restrict__ W_out, const float* __restrict__ b_out,
                    const float* __restrict__ Wih0, const float* __restrict__ Whh0,
                    const float* __restrict__ bih0, const float* __restrict__ bhh0,
                    const float* __restrict__ Wih1, const float* __restrict__ Whh1,
                    const float* __restrict__ bih1, const float* __restrict__ bhh1,
                    const float* __restrict__ Wih2, const float* __restrict__ Whh2,
                    const float* __restrict__ bih2, const float* __restrict__ bhh2,
                    float* __restrict__ out)
{
    const int tid = threadIdx.x;
    const int wid = tid >> 6;      // 0..2 layer waves, 3 = projection wave
    const int l   = tid & 63;
    const int n   = l & 15;
    const int g   = l >> 4;
    const int b0  = blockIdx.x * 32 + n;   // pipe p owns batch col b0 + 16p

    __shared__ uint2v lbuf[2][2][2][4][64];  // 16 KiB [pipe][parity][producer][slot][lane]
    __shared__ f32x4  obuf[2][2][4][64];     // 16 KiB [pipe][parity][slot][lane]

    const int lw = wid < 3 ? wid : 2;
    const float* Wih = lw == 0 ? Wih0 : (lw == 1 ? Wih1 : Wih2);
    const float* Whh = lw == 0 ? Whh0 : (lw == 1 ? Whh1 : Whh2);
    const float* bih = lw == 0 ? bih0 : (lw == 1 ? bih1 : bih2);
    const float* bhh = lw == 0 ? bhh0 : (lw == 1 ? bhh1 : bhh2);

    // Fused A-fragments (f16, scale folded), SHARED by both pipes: row m=n, k=8g+j.
    f16x8 aR, aZ, aNX, aNH;
#pragma unroll
    for (int q = 0; q < 4; ++q) {
        const int c = 4 * g + q;
        aR[q]      = (_Float16)(KS1 * Wih[(0 * 16 + n) * 16 + c]);
        aR[4 + q]  = (_Float16)(KS1 * Whh[(0 * 16 + n) * 16 + c]);
        aZ[q]      = (_Float16)(KS1 * Wih[(1 * 16 + n) * 16 + c]);
        aZ[4 + q]  = (_Float16)(KS1 * Whh[(1 * 16 + n) * 16 + c]);
        aNX[q]     = (_Float16)(KS2 * Wih[(2 * 16 + n) * 16 + c]);
        aNX[4 + q] = (_Float16)0.0f;
        aNH[q]     = (_Float16)0.0f;
        aNH[4 + q] = (_Float16)(KS2 * Whh[(2 * 16 + n) * 16 + c]);
    }

    // Scaled biases in C layout (row m = 4g+j)
    f32x4 bR, bZ, bNX, bNH;
#pragma unroll
    for (int j = 0; j < 4; ++j) {
        const int m = 4 * g + j;
        bR[j]  = KS1 * (bih[m]      + bhh[m]);
        bZ[j]  = KS1 * (bih[16 + m] + bhh[16 + m]);
        bNX[j] = KS2 * bih[32 + m];
        bNH[j] = KS2 * bhh[32 + m];
    }

    // Embedding rows c = 4g+q (wave 0)
    float wex[4], wey[4], beq[4];
#pragma unroll
    for (int q = 0; q < 4; ++q) {
        const int c = 4 * g + q;
        wex[q] = W_emb[c * 2]; wey[q] = W_emb[c * 2 + 1]; beq[q] = b_emb[c];
    }
    // Output weights rows m = 4g+j (wave 3)
    float wo0[4], wo1[4];
#pragma unroll
    for (int j = 0; j < 4; ++j) { wo0[j] = W_out[4 * g + j]; wo1[j] = W_out[16 + 4 * g + j]; }
    const float bo0 = b_out[0], bo1 = b_out[1];

    // Per-pipe hidden state (f32 C rows + packed f16 halves)
    f32x4  hC[2];
    uint2v hPK[2];
#pragma unroll
    for (int p = 0; p < 2; ++p) {
        hC[p] = *(const f32x4*)(h0 + ((size_t)lw * BB + b0 + 16 * p) * 16 + 4 * g);
        hPK[p].x = pk2(hC[p][0], hC[p][1]);
        hPK[p].y = pk2(hC[p][2], hC[p][3]);
    }

    const float* xb[2] = { x + (size_t)b0 * (TT * 2), x + (size_t)(b0 + 16) * (TT * 2) };
    float4 xc0[2], xc1[2];
    if (wid == 0) {
#pragma unroll
        for (int p = 0; p < 2; ++p) {
            xc0[p] = *(const float4*)(xb[p]);
            xc1[p] = *(const float4*)(xb[p] + 4);
        }
    }

    const int NS = TT / 4 + 3;   // 131 supersteps
    for (int s = 0; s < NS; ++s) {
        const int t0 = 4 * (s - wid);
        if (t0 >= 0 && t0 < TT) {
            if (wid < 3) {
                // ---- input fragments for both pipes, t0..t0+3 (lane-aligned) ----
                uint2v inV[2][4];
                if (wid == 0) {
#pragma unroll
                    for (int p = 0; p < 2; ++p) {
                        f32x4 e0, e1, e2, e3;
#pragma unroll
                        for (int q = 0; q < 4; ++q) {
                            e0[q] = fmaxf(fmaf(wey[q], xc0[p].y, fmaf(wex[q], xc0[p].x, beq[q])), 0.0f);
                            e1[q] = fmaxf(fmaf(wey[q], xc0[p].w, fmaf(wex[q], xc0[p].z, beq[q])), 0.0f);
                            e2[q] = fmaxf(fmaf(wey[q], xc1[p].y, fmaf(wex[q], xc1[p].x, beq[q])), 0.0f);
                            e3[q] = fmaxf(fmaf(wey[q], xc1[p].w, fmaf(wex[q], xc1[p].z, beq[q])), 0.0f);
                        }
                        inV[p][0].x = pk2(e0[0], e0[1]); inV[p][0].y = pk2(e0[2], e0[3]);
                        inV[p][1].x = pk2(e1[0], e1[1]); inV[p][1].y = pk2(e1[2], e1[3]);
                        inV[p][2].x = pk2(e2[0], e2[1]); inV[p][2].y = pk2(e2[2], e2[3]);
                        inV[p][3].x = pk2(e3[0], e3[1]); inV[p][3].y = pk2(e3[2], e3[3]);
                        if (t0 + 4 < TT) {
                            xc0[p] = *(const float4*)(xb[p] + (t0 + 4) * 2);
                            xc1[p] = *(const float4*)(xb[p] + (t0 + 4) * 2 + 4);
                        }
                    }
                } else {
                    const int pp = (s - 1) & 1;
#pragma unroll
                    for (int p = 0; p < 2; ++p)
#pragma unroll
                        for (int i = 0; i < 4; ++i)
                            inV[p][i] = lbuf[p][pp][wid - 1][i][l];
                }

                // ---- 4 timestep slots; per slot: 8 MFMAs then 8 gate chains ----
#pragma unroll
                for (int i = 0; i < 4; ++i) {
                    f32x4 ar[2], az[2], anx[2], anh[2];
#pragma unroll
                    for (int p = 0; p < 2; ++p) {
                        uint4v bw;
                        bw.x = inV[p][i].x; bw.y = inV[p][i].y;
                        bw.z = hPK[p].x;    bw.w = hPK[p].y;
                        const f16x8 Bf = __builtin_bit_cast(f16x8, bw);
                        ar[p]  = MFMA16(aR,  Bf, bR);
                        az[p]  = MFMA16(aZ,  Bf, bZ);
                        anx[p] = MFMA16(aNX, Bf, bNX);
                        anh[p] = MFMA16(aNH, Bf, bNH);
                    }
#pragma unroll
                    for (int p = 0; p < 2; ++p) {
#pragma unroll
                        for (int j = 0; j < 4; ++j) {
                            const float r = fast_rcp(1.0f + exp2f(ar[p][j]));
                            const float z = fast_rcp(1.0f + exp2f(az[p][j]));
                            const float En = exp2f(fmaf(r, anh[p][j], anx[p][j]));
                            const float nn = fmaf(2.0f, fast_rcp(1.0f + En), -1.0f);
                            hC[p][j] = fmaf(z, hC[p][j] - nn, nn);
                        }
                        hPK[p].x = pk2(hC[p][0], hC[p][1]);
                        hPK[p].y = pk2(hC[p][2], hC[p][3]);
                        if (wid < 2) lbuf[p][s & 1][wid][i][l] = hPK[p];
                        else         obuf[p][s & 1][i][l] = hC[p];
                    }
                }
            } else {
                // ---- projection wave: both pipes, t0..t0+3 (h2 from wave2, s-1) ----
                const int pp = (s - 1) & 1;
#pragma unroll
                for (int p = 0; p < 2; ++p) {
                    float pr[8];
#pragma unroll
                    for (int i = 0; i < 4; ++i) {
                        const f32x4 h2 = obuf[p][pp][i][l];
                        float p0 = 0.f, p1 = 0.f;
#pragma unroll
                        for (int j = 0; j < 4; ++j) {
                            p0 = fmaf(wo0[j], h2[j], p0);
                            p1 = fmaf(wo1[j], h2[j], p1);
                        }
                        p0 += __shfl_xor(p0, 16); p0 += __shfl_xor(p0, 32);
                        p1 += __shfl_xor(p1, 16); p1 += __shfl_xor(p1, 32);
                        pr[2 * i] = p0 + bo0; pr[2 * i + 1] = p1 + bo1;
                    }
                    if (g == 0) {
                        float* op = out + (size_t)(b0 + 16 * p) * (TT * 2) + t0 * 2;
                        *(float4*)(op)     = make_float4(pr[0], pr[1], pr[2], pr[3]);
                        *(float4*)(op + 4) = make_float4(pr[4], pr[5], pr[6], pr[7]);
                    }
                }
            }
        }
        // LDS-only barrier: drain ds ops, fence compiler, s_barrier.
        // vm loads/stores (x prefetch, out stores) deliberately stay in flight.
        asm volatile("s_waitcnt lgkmcnt(0)\n\ts_barrier" ::: "memory");
    }

    // Final hidden state: layer waves store their own layer, both pipes.
    if (wid < 3) {
#pragma unroll
        for (int p = 0; p < 2; ++p)
            *(f32x4*)(out + (size_t)BB * TT * 2
                      + ((size_t)wid * BB + b0 + 16 * p) * 16 + 4 * g) = hC[p];
    }
}

extern "C" void kernel_launch(void* const* d_in, const int* in_sizes, int n_in,
                              void* d_out, int out_size, void* d_ws, size_t ws_size,
                              hipStream_t stream) {
    const float* x     = (const float*)d_in[0];
    const float* h0    = (const float*)d_in[1];
    const float* W_emb = (const float*)d_in[2];
    const float* b_emb = (const float*)d_in[3];
    const float* W_out = (const float*)d_in[4];
    const float* b_out = (const float*)d_in[5];
    const float* Wih0  = (const float*)d_in[6];
    const float* Whh0  = (const float*)d_in[7];
    const float* bih0  = (const float*)d_in[8];
    const float* bhh0  = (const float*)d_in[9];
    const float* Wih1  = (const float*)d_in[10];
    const float* Whh1  = (const float*)d_in[11];
    const float* bih1  = (const float*)d_in[12];
    const float* bhh1  = (const float*)d_in[13];
    const float* Wih2  = (const float*)d_in[14];
    const float* Whh2  = (const float*)d_in[15];
    const float* bih2  = (const float*)d_in[16];
    const float* bhh2  = (const float*)d_in[17];
    float* out = (float*)d_out;

    gru_fk2_kernel<<<dim3(BB / 32), dim3(256), 0, stream>>>(
        x, h0, W_emb, b_emb, W_out, b_out,
        Wih0, Whh0, bih0, bhh0,
        Wih1, Whh1, bih1, bhh1,
        Wih2, Whh2, bih2, bhh2,
        out);
}

// Round 12
// 187.111 us; speedup vs baseline: 2.0878x; 2.0878x over previous
//
#include <hip/hip_runtime.h>
#include <hip/hip_bf16.h>

#define TT 512
#define BB 4096

typedef __attribute__((ext_vector_type(4))) float f32x4;
typedef __attribute__((ext_vector_type(8))) _Float16 f16x8;
typedef __attribute__((ext_vector_type(4))) unsigned int uint4v;

__device__ __forceinline__ f32x4 MFMA16(f16x8 a, f16x8 b, f32x4 c) {
    return __builtin_amdgcn_mfma_f32_16x16x32_f16(a, b, c, 0, 0, 0);
}
__device__ __forceinline__ float fast_rcp(float x) { return __builtin_amdgcn_rcpf(x); }
__device__ __forceinline__ unsigned int pkdup(float a) {
    return __builtin_bit_cast(unsigned int, __builtin_amdgcn_cvt_pkrtz(a, a));
}

// Layer-pipelined GRU (R8 skeleton, validated): 4 waves, 4 t/superstep,
//   waves 0..2 = layers (wave L does t=4(s-L)..+3), wave 3 = projection+stores.
// Block = 256 thr, one 16-batch tile; grid = 256 (1 wave/SIMD chip-wide).
// f16 MFMA, K=32 pair-slot layout: k = 2c+p, c = 4g+(j>>1) logical dim;
//   A[2q] = (+/-scaled) W[n][4g+q], A[2q+1] = 0;  B[2q] = B[2q+1] = v[4g+q].
// Gate algebra (sign/scale folded into W: r,z rows x -1; n rows x -2):
//   Er = e^{-s_r}, Ez = e^{-s_z}, En = e^{-2 s_n};  r = 1/(1+Er)
//   h' = [h(1+En) + Ez(1-En)] / [(1+Ez)(1+En)]   (ONE rcp for z+tanh combined)
__global__ __launch_bounds__(256, 1)
void gru_p4f_kernel(const float* __restrict__ x, const float* __restrict__ h0,
                    const float* __restrict__ W_emb, const float* __restrict__ b_emb,
                    const float* __restrict__ W_out, const float* __restrict__ b_out,
                    const float* __restrict__ Wih0, const float* __restrict__ Whh0,
                    const float* __restrict__ bih0, const float* __restrict__ bhh0,
                    const float* __restrict__ Wih1, const float* __restrict__ Whh1,
                    const float* __restrict__ bih1, const float* __restrict__ bhh1,
                    const float* __restrict__ Wih2, const float* __restrict__ Whh2,
                    const float* __restrict__ bih2, const float* __restrict__ bhh2,
                    float* __restrict__ out)
{
    const int tid = threadIdx.x;
    const int wid = tid >> 6;      // 0..2 layer waves, 3 = projection wave
    const int l   = tid & 63;
    const int n   = l & 15;
    const int g   = l >> 4;
    const int b   = blockIdx.x * 16 + n;

    __shared__ uint4v lbuf[2][2][4][64];  // 16 KiB [parity][producer L][tslot][lane] dup'd f16x8
    __shared__ f32x4  obuf[2][4][64];     //  8 KiB [parity][tslot][lane] h2 f32

    const int lw = wid < 3 ? wid : 2;
    const float* Wih = lw == 0 ? Wih0 : (lw == 1 ? Wih1 : Wih2);
    const float* Whh = lw == 0 ? Whh0 : (lw == 1 ? Whh1 : Whh2);
    const float* bih = lw == 0 ? bih0 : (lw == 1 ? bih1 : bih2);
    const float* bhh = lw == 0 ? bhh0 : (lw == 1 ? bhh1 : bhh2);

    // A-fragments, f16, sign/scale folded: gate 0,1 (r,z) x -1 ; gate 2 (n) x -2.
    f16x8 aX[3], aH[3];
#pragma unroll
    for (int gate = 0; gate < 3; ++gate) {
        const float ks = (gate == 2) ? -2.0f : -1.0f;
        f16x8 fx, fh;
#pragma unroll
        for (int q = 0; q < 4; ++q) {
            fx[2 * q]     = (_Float16)(ks * Wih[(gate * 16 + n) * 16 + 4 * g + q]);
            fx[2 * q + 1] = (_Float16)0.0f;
            fh[2 * q]     = (_Float16)(ks * Whh[(gate * 16 + n) * 16 + 4 * g + q]);
            fh[2 * q + 1] = (_Float16)0.0f;
        }
        aX[gate] = fx; aH[gate] = fh;
    }

    // Scaled biases in C layout (row m = 4g+j)
    f32x4 bR, bZ, bNX, bNH;
#pragma unroll
    for (int j = 0; j < 4; ++j) {
        const int m = 4 * g + j;
        bR[j]  = -1.0f * (bih[m]      + bhh[m]);
        bZ[j]  = -1.0f * (bih[16 + m] + bhh[16 + m]);
        bNX[j] = -2.0f * bih[32 + m];
        bNH[j] = -2.0f * bhh[32 + m];
    }

    // Embedding rows c = 4g+q (wave 0)
    float wex[4], wey[4], beq[4];
#pragma unroll
    for (int q = 0; q < 4; ++q) {
        const int c = 4 * g + q;
        wex[q] = W_emb[c * 2]; wey[q] = W_emb[c * 2 + 1]; beq[q] = b_emb[c];
    }
    // Output weights rows m = 4g+j (wave 3)
    float wo0[4], wo1[4];
#pragma unroll
    for (int j = 0; j < 4; ++j) { wo0[j] = W_out[4 * g + j]; wo1[j] = W_out[16 + 4 * g + j]; }
    const float bo0 = b_out[0], bo1 = b_out[1];

    // Hidden state: f32 C rows + dup'd f16 B fragment
    f32x4 hC = *(const f32x4*)(h0 + ((size_t)lw * BB + b) * 16 + 4 * g);
    uint4v hB4;
#pragma unroll
    for (int q = 0; q < 4; ++q) hB4[q] = pkdup(hC[q]);

    const float* xb = x + (size_t)b * (TT * 2);
    float4 xc0 = make_float4(0.f, 0.f, 0.f, 0.f), xc1 = xc0;
    if (wid == 0) { xc0 = *(const float4*)xb; xc1 = *(const float4*)(xb + 4); }

#define HB() __builtin_bit_cast(f16x8, hB4)

#define GATES(AR, AZ, ANH, ANX)                                           \
    do {                                                                  \
        _Pragma("unroll")                                                 \
        for (int j = 0; j < 4; ++j) {                                     \
            const float Er = __expf(AR[j]);                               \
            const float Ez = __expf(AZ[j]);                               \
            const float r  = fast_rcp(1.0f + Er);                         \
            const float En = __expf(fmaf(r, ANH[j], ANX[j]));             \
            const float num = fmaf(En, hC[j] - Ez, hC[j] + Ez);           \
            const float den = fmaf(En, Ez, En) + (1.0f + Ez);             \
            hC[j] = num * fast_rcp(den);                                  \
        }                                                                 \
        _Pragma("unroll")                                                 \
        for (int q = 0; q < 4; ++q) hB4[q] = pkdup(hC[q]);                \
    } while (0)

#define HANDOFF(i)                                                        \
    do {                                                                  \
        if (wid < 2) lbuf[s & 1][wid][i][l] = hB4;                        \
        else         obuf[s & 1][i][l] = hC;                              \
    } while (0)

    const int NS = TT / 4 + 3;   // 131 supersteps
    for (int s = 0; s < NS; ++s) {
        const int t0 = 4 * (s - wid);
        if (t0 >= 0 && t0 < TT) {
            if (wid < 3) {
                // ---- input B-fragments (dup'd f16) for t0..t0+3 ----
                f16x8 B0, B1, B2, B3;
                if (wid == 0) {
                    uint4v u0, u1, u2, u3;
#pragma unroll
                    for (int q = 0; q < 4; ++q) {
                        u0[q] = pkdup(fmaxf(fmaf(wey[q], xc0.y, fmaf(wex[q], xc0.x, beq[q])), 0.0f));
                        u1[q] = pkdup(fmaxf(fmaf(wey[q], xc0.w, fmaf(wex[q], xc0.z, beq[q])), 0.0f));
                        u2[q] = pkdup(fmaxf(fmaf(wey[q], xc1.y, fmaf(wex[q], xc1.x, beq[q])), 0.0f));
                        u3[q] = pkdup(fmaxf(fmaf(wey[q], xc1.w, fmaf(wex[q], xc1.z, beq[q])), 0.0f));
                    }
                    B0 = __builtin_bit_cast(f16x8, u0);
                    B1 = __builtin_bit_cast(f16x8, u1);
                    B2 = __builtin_bit_cast(f16x8, u2);
                    B3 = __builtin_bit_cast(f16x8, u3);
                    if (t0 + 4 < TT) {
                        xc0 = *(const float4*)(xb + (t0 + 4) * 2);
                        xc1 = *(const float4*)(xb + (t0 + 4) * 2 + 4);
                    }
                } else {
                    const int pp = (s - 1) & 1;
                    B0 = __builtin_bit_cast(f16x8, lbuf[pp][wid - 1][0][l]);
                    B1 = __builtin_bit_cast(f16x8, lbuf[pp][wid - 1][1][l]);
                    B2 = __builtin_bit_cast(f16x8, lbuf[pp][wid - 1][2][l]);
                    B3 = __builtin_bit_cast(f16x8, lbuf[pp][wid - 1][3][l]);
                }

                // ---- t0: h-side first (bias C), x chained when B0 ready ----
                f32x4 arA  = MFMA16(aH[0], HB(), bR);
                f32x4 azA  = MFMA16(aH[1], HB(), bZ);
                f32x4 anhA = MFMA16(aH[2], HB(), bNH);
                f32x4 anxA = MFMA16(aX[2], B0, bNX);
                arA = MFMA16(aX[0], B0, arA);
                azA = MFMA16(aX[1], B0, azA);
                // pre-issue t1 x-side (fills MFMA pipe during t0 gates)
                f32x4 arB  = MFMA16(aX[0], B1, bR);
                f32x4 azB  = MFMA16(aX[1], B1, bZ);
                f32x4 anxB = MFMA16(aX[2], B1, bNX);
                GATES(arA, azA, anhA, anxA);
                HANDOFF(0);
                // ---- t1 ----
                f32x4 anhB = MFMA16(aH[2], HB(), bNH);
                arB = MFMA16(aH[0], HB(), arB);
                azB = MFMA16(aH[1], HB(), azB);
                arA  = MFMA16(aX[0], B2, bR);     // pre-issue t2 x-side
                azA  = MFMA16(aX[1], B2, bZ);
                anxA = MFMA16(aX[2], B2, bNX);
                GATES(arB, azB, anhB, anxB);
                HANDOFF(1);
                // ---- t2 ----
                anhA = MFMA16(aH[2], HB(), bNH);
                arA = MFMA16(aH[0], HB(), arA);
                azA = MFMA16(aH[1], HB(), azA);
                arB  = MFMA16(aX[0], B3, bR);     // pre-issue t3 x-side
                azB  = MFMA16(aX[1], B3, bZ);
                anxB = MFMA16(aX[2], B3, bNX);
                GATES(arA, azA, anhA, anxA);
                HANDOFF(2);
                // ---- t3 ----
                anhB = MFMA16(aH[2], HB(), bNH);
                arB = MFMA16(aH[0], HB(), arB);
                azB = MFMA16(aH[1], HB(), azB);
                GATES(arB, azB, anhB, anxB);
                HANDOFF(3);
            } else {
                // ---- projection wave: t0..t0+3 (h2 from wave2, superstep s-1) ----
                const int pp = (s - 1) & 1;
                float pr[8];
#pragma unroll
                for (int i = 0; i < 4; ++i) {
                    const f32x4 h2 = obuf[pp][i][l];
                    float p0 = 0.f, p1 = 0.f;
#pragma unroll
                    for (int j = 0; j < 4; ++j) {
                        p0 = fmaf(wo0[j], h2[j], p0);
                        p1 = fmaf(wo1[j], h2[j], p1);
                    }
                    p0 += __shfl_xor(p0, 16); p0 += __shfl_xor(p0, 32);
                    p1 += __shfl_xor(p1, 16); p1 += __shfl_xor(p1, 32);
                    pr[2 * i] = p0 + bo0; pr[2 * i + 1] = p1 + bo1;
                }
                if (g == 0) {
                    float* op = out + (size_t)b * (TT * 2) + t0 * 2;
                    *(float4*)(op)     = make_float4(pr[0], pr[1], pr[2], pr[3]);
                    *(float4*)(op + 4) = make_float4(pr[4], pr[5], pr[6], pr[7]);
                }
            }
        }
        // LDS-only barrier: drain ds ops, fence compiler, s_barrier.
        // vm loads/stores (x prefetch, out stores) deliberately stay in flight.
        asm volatile("s_waitcnt lgkmcnt(0)\n\ts_barrier" ::: "memory");
    }

    // Final hidden state: layer waves store their own layer.
    if (wid < 3)
        *(f32x4*)(out + (size_t)BB * TT * 2 + ((size_t)wid * BB + b) * 16 + 4 * g) = hC;

#undef GATES
#undef HANDOFF
#undef HB
}

extern "C" void kernel_launch(void* const* d_in, const int* in_sizes, int n_in,
                              void* d_out, int out_size, void* d_ws, size_t ws_size,
                              hipStream_t stream) {
    const float* x     = (const float*)d_in[0];
    const float* h0    = (const float*)d_in[1];
    const float* W_emb = (const float*)d_in[2];
    const float* b_emb = (const float*)d_in[3];
    const float* W_out = (const float*)d_in[4];
    const float* b_out = (const float*)d_in[5];
    const float* Wih0  = (const float*)d_in[6];
    const float* Whh0  = (const float*)d_in[7];
    const float* bih0  = (const float*)d_in[8];
    const float* bhh0  = (const float*)d_in[9];
    const float* Wih1  = (const float*)d_in[10];
    const float* Whh1  = (const float*)d_in[11];
    const float* bih1  = (const float*)d_in[12];
    const float* bhh1  = (const float*)d_in[13];
    const float* Wih2  = (const float*)d_in[14];
    const float* Whh2  = (const float*)d_in[15];
    const float* bih2  = (const float*)d_in[16];
    const float* bhh2  = (const float*)d_in[17];
    float* out = (float*)d_out;

    gru_p4f_kernel<<<dim3(BB / 16), dim3(256), 0, stream>>>(
        x, h0, W_emb, b_emb, W_out, b_out,
        Wih0, Whh0, bih0, bhh0,
        Wih1, Whh1, bih1, bhh1,
        Wih2, Whh2, bih2, bhh2,
        out);
}